// Round 4
// baseline (1039.120 us; speedup 1.0000x reference)
//
#include <hip/hip_runtime.h>

#define N_NODES   100000
#define N_EDGES   1600000
#define D         64
#define N_TARGETS 100
#define N_GRAPHS  512
#define NBUCK     391      // ceil(N_NODES/256)
#define PDEPTH    48       // LDS bucket depth in k_part

// ---------------- utility ----------------

__global__ void k_zero_i(int* __restrict__ p, int n) {
    int i = blockIdx.x * blockDim.x + threadIdx.x;
    if (i < n) p[i] = 0;
}
__global__ void k_zero_f(float* __restrict__ p, int n) {
    int i = blockIdx.x * blockDim.x + threadIdx.x;
    if (i < n) p[i] = 0.0f;
}

// ---------------- CSR build ----------------

__global__ void k_deg(const int* __restrict__ dst, int* __restrict__ deg) {
    int e = blockIdx.x * blockDim.x + threadIdx.x;
    if (e < N_EDGES) atomicAdd(&deg[dst[e]], 1);
}

__global__ void k_dinv(const int* __restrict__ deg, float* __restrict__ dinv) {
    int i = blockIdx.x * blockDim.x + threadIdx.x;
    if (i < N_NODES) dinv[i] = rsqrtf((float)deg[i] + 1.0f);  // +1 self-loop
}

// per-256-node-bucket edge totals
__global__ void k_bsum(const int* __restrict__ deg, int* __restrict__ bsum) {
    __shared__ int s[256];
    int t = threadIdx.x, i = blockIdx.x * 256 + t;
    s[t] = (i < N_NODES) ? deg[i] : 0;
    __syncthreads();
    for (int off = 128; off > 0; off >>= 1) {
        if (t < off) s[t] += s[t + off];
        __syncthreads();
    }
    if (t == 0) bsum[blockIdx.x] = s[0];
}

// exclusive scan of 391 bucket sums; also writes bsum[NBUCK]=E and inits gcur
__global__ void k_scan2(int* __restrict__ bsum, int* __restrict__ gcur) {
    __shared__ int s[512];
    int t = threadIdx.x;
    int v = (t < NBUCK) ? bsum[t] : 0;
    s[t] = v;
    __syncthreads();
    for (int off = 1; off < 512; off <<= 1) {
        int x = (t >= off) ? s[t - off] : 0;
        __syncthreads();
        s[t] += x;
        __syncthreads();
    }
    if (t <= NBUCK) bsum[t] = s[t] - v;   // t==NBUCK -> total = N_EDGES
    if (t < NBUCK)  gcur[t] = s[t] - v;
}

// pass A: LDS-bucketed partition of edges into dst-buckets (packed u32)
__global__ void __launch_bounds__(256)
k_part(const int* __restrict__ src, const int* __restrict__ dst,
       int* __restrict__ gcur, unsigned* __restrict__ ebuck) {
    __shared__ unsigned buf[NBUCK * PDEPTH];
    __shared__ int cnt[NBUCK];
    int tid = threadIdx.x;
    for (int q = tid; q < NBUCK; q += 256) cnt[q] = 0;
    __syncthreads();

    const int per = N_EDGES / 256;  // 6250, exact (grid = 256 blocks)
    int start = blockIdx.x * per, end = start + per;
    for (int e = start + tid; e < end; e += 256) {
        int d = dst[e];
        int b = d >> 8;
        unsigned pk = ((unsigned)(d & 255) << 17) | (unsigned)src[e];
        int p = atomicAdd(&cnt[b], 1);
        if (p < PDEPTH) buf[b * PDEPTH + p] = pk;
        else { int gp = atomicAdd(&gcur[b], 1); ebuck[gp] = pk; }  // rare
    }
    __syncthreads();

    // flush: wave-cooperative, coalesced chunk per bucket
    int lane = tid & 63, wave = tid >> 6;
    for (int b = wave; b < NBUCK; b += 4) {
        int c = cnt[b]; if (c > PDEPTH) c = PDEPTH;
        if (c == 0) continue;
        int gp = 0;
        if (lane == 0) gp = atomicAdd(&gcur[b], c);
        gp = __shfl(gp, 0, 64);
        if (lane < c) ebuck[gp + lane] = buf[b * PDEPTH + lane];
    }
}

// pass B: one block per bucket; local scan of deg -> node bases; LDS cursors;
// all esrc writes land in this block's private contiguous window.
__global__ void __launch_bounds__(256)
k_fill2(const unsigned* __restrict__ ebuck, const int* __restrict__ deg,
        const int* __restrict__ bsum, int* __restrict__ base, int* __restrict__ esrc) {
    __shared__ int s[256];
    __shared__ int nbase[256];
    __shared__ int lcur[256];
    int b = blockIdx.x, tid = threadIdx.x;
    int gnode = b * 256 + tid;
    int bucketBase = bsum[b], bucketEnd = bsum[b + 1];
    int d = (gnode < N_NODES) ? deg[gnode] : 0;
    s[tid] = d;
    __syncthreads();
    for (int off = 1; off < 256; off <<= 1) {
        int x = (tid >= off) ? s[tid - off] : 0;
        __syncthreads();
        s[tid] += x;
        __syncthreads();
    }
    int excl = s[tid] - d;
    nbase[tid] = excl;
    lcur[tid] = 0;
    if (gnode < N_NODES) base[gnode] = bucketBase + excl;
    if (gnode == N_NODES) base[N_NODES] = N_EDGES;
    __syncthreads();
    for (int p = bucketBase + tid; p < bucketEnd; p += 256) {
        unsigned pk = ebuck[p];
        int dl = (int)(pk >> 17);
        int sv = (int)(pk & 0x1FFFF);
        int pos = bucketBase + nbase[dl] + atomicAdd(&lcur[dl], 1);
        esrc[pos] = sv;
    }
}

// ---------------- matmul: Y[row] = (relu?)X[row] @ W * dinv[row] ----------------
__global__ void __launch_bounds__(256)
k_mm(const float* __restrict__ X, const float* __restrict__ W,
     const float* __restrict__ dinv, float* __restrict__ Y, int relu) {
    __shared__ float Xs[64][68];
    __shared__ float Ws[64][68];
    int tid = threadIdx.x;
    int r0  = blockIdx.x * 64;
    {
        int lr = tid >> 4;
        int lc = (tid & 15) * 4;
#pragma unroll
        for (int i = 0; i < 4; ++i) {
            int row = lr + 16 * i;
            *(float4*)&Ws[row][lc] = *(const float4*)(W + row * 64 + lc);
            int gr = r0 + row;
            if (gr < N_NODES) {
                float4 xv = *(const float4*)(X + (size_t)gr * 64 + lc);
                if (relu) {
                    xv.x = fmaxf(xv.x, 0.0f); xv.y = fmaxf(xv.y, 0.0f);
                    xv.z = fmaxf(xv.z, 0.0f); xv.w = fmaxf(xv.w, 0.0f);
                }
                *(float4*)&Xs[row][lc] = xv;
            }
        }
    }
    __syncthreads();

    int tx = (tid & 15) * 4;
    int ty = (tid >> 4) * 4;
    float acc[4][4] = {{0.f}};

#pragma unroll
    for (int kk = 0; kk < 16; ++kk) {
        float4 a[4], w[4];
#pragma unroll
        for (int r = 0; r < 4; ++r) a[r] = *(float4*)&Xs[ty + r][kk * 4];
#pragma unroll
        for (int k = 0; k < 4; ++k) w[k] = *(float4*)&Ws[kk * 4 + k][tx];
#pragma unroll
        for (int r = 0; r < 4; ++r) {
#pragma unroll
            for (int k = 0; k < 4; ++k) {
                float av = ((const float*)&a[r])[k];
                acc[r][0] = fmaf(av, w[k].x, acc[r][0]);
                acc[r][1] = fmaf(av, w[k].y, acc[r][1]);
                acc[r][2] = fmaf(av, w[k].z, acc[r][2]);
                acc[r][3] = fmaf(av, w[k].w, acc[r][3]);
            }
        }
    }

#pragma unroll
    for (int r = 0; r < 4; ++r) {
        int gr = r0 + ty + r;
        if (gr < N_NODES) {
            float di = dinv[gr];
            float4 o = { acc[r][0] * di, acc[r][1] * di, acc[r][2] * di, acc[r][3] * di };
            *(float4*)(Y + (size_t)gr * 64 + tx) = o;
        }
    }
}

// ---------------- pull aggregation (float4-lane layout) ----------------
// Wave = node. lane = 16*g + l: slot g in [0,4) handles edges j+g, lane-part l
// holds features [4l,4l+4). One dwordx4 wave-instruction gathers 4 edge rows
// (1KB); unroll x2 keeps 2KB in flight. Cross-slot sum via shfl_xor at end.
__global__ void __launch_bounds__(256)
k_pull(const float* __restrict__ H, const int* __restrict__ esrc,
       const int* __restrict__ base, const float* __restrict__ dinv,
       const float* __restrict__ b, float* __restrict__ AGG) {
    int i    = blockIdx.x * 4 + (threadIdx.x >> 6);
    int lane = threadIdx.x & 63;
    int g = lane >> 4, l = lane & 15;
    int s0 = base[i], s1 = base[i + 1];
    float4 acc = {0.f, 0.f, 0.f, 0.f};
    if (g == 0) acc = *(const float4*)(H + (size_t)i * D + l * 4);  // self term

    int p = s0;
    while (p < s1) {
        int cnt = s1 - p;
        if (cnt > 64) cnt = 64;
        int ed = (lane < cnt) ? esrc[p + lane] : 0;
        int j = 0;
        for (; j + 8 <= cnt; j += 8) {
            int e0 = __shfl(ed, j + g, 64);
            int e1 = __shfl(ed, j + 4 + g, 64);
            float4 v0 = *(const float4*)(H + (size_t)e0 * D + l * 4);
            float4 v1 = *(const float4*)(H + (size_t)e1 * D + l * 4);
            acc.x += v0.x + v1.x; acc.y += v0.y + v1.y;
            acc.z += v0.z + v1.z; acc.w += v0.w + v1.w;
        }
        for (; j < cnt; j += 4) {
            int e0 = __shfl(ed, (j + g) & 63, 64);
            if (j + g < cnt) {
                float4 v0 = *(const float4*)(H + (size_t)e0 * D + l * 4);
                acc.x += v0.x; acc.y += v0.y; acc.z += v0.z; acc.w += v0.w;
            }
        }
        p += cnt;
    }
    // reduce across the 4 slots
    acc.x += __shfl_xor(acc.x, 16, 64); acc.y += __shfl_xor(acc.y, 16, 64);
    acc.z += __shfl_xor(acc.z, 16, 64); acc.w += __shfl_xor(acc.w, 16, 64);
    acc.x += __shfl_xor(acc.x, 32, 64); acc.y += __shfl_xor(acc.y, 32, 64);
    acc.z += __shfl_xor(acc.z, 32, 64); acc.w += __shfl_xor(acc.w, 32, 64);

    if (g == 0) {
        float di = dinv[i];
        float4 bl = *(const float4*)(b + l * 4);
        float4 o = { fmaf(acc.x, di, bl.x), fmaf(acc.y, di, bl.y),
                     fmaf(acc.z, di, bl.z), fmaf(acc.w, di, bl.w) };
        *(float4*)(AGG + (size_t)i * D + l * 4) = o;
    }
}

// layer-3 variant: fused graph mean-pool accumulation
__global__ void __launch_bounds__(256)
k_pull_pool(const float* __restrict__ H, const int* __restrict__ esrc,
            const int* __restrict__ base, const float* __restrict__ dinv,
            const float* __restrict__ b, const int* __restrict__ seg,
            float* __restrict__ pooled) {
    int i    = blockIdx.x * 4 + (threadIdx.x >> 6);
    int lane = threadIdx.x & 63;
    int g = lane >> 4, l = lane & 15;
    int s0 = base[i], s1 = base[i + 1];
    float4 acc = {0.f, 0.f, 0.f, 0.f};
    if (g == 0) acc = *(const float4*)(H + (size_t)i * D + l * 4);

    int p = s0;
    while (p < s1) {
        int cnt = s1 - p;
        if (cnt > 64) cnt = 64;
        int ed = (lane < cnt) ? esrc[p + lane] : 0;
        int j = 0;
        for (; j + 8 <= cnt; j += 8) {
            int e0 = __shfl(ed, j + g, 64);
            int e1 = __shfl(ed, j + 4 + g, 64);
            float4 v0 = *(const float4*)(H + (size_t)e0 * D + l * 4);
            float4 v1 = *(const float4*)(H + (size_t)e1 * D + l * 4);
            acc.x += v0.x + v1.x; acc.y += v0.y + v1.y;
            acc.z += v0.z + v1.z; acc.w += v0.w + v1.w;
        }
        for (; j < cnt; j += 4) {
            int e0 = __shfl(ed, (j + g) & 63, 64);
            if (j + g < cnt) {
                float4 v0 = *(const float4*)(H + (size_t)e0 * D + l * 4);
                acc.x += v0.x; acc.y += v0.y; acc.z += v0.z; acc.w += v0.w;
            }
        }
        p += cnt;
    }
    acc.x += __shfl_xor(acc.x, 16, 64); acc.y += __shfl_xor(acc.y, 16, 64);
    acc.z += __shfl_xor(acc.z, 16, 64); acc.w += __shfl_xor(acc.w, 16, 64);
    acc.x += __shfl_xor(acc.x, 32, 64); acc.y += __shfl_xor(acc.y, 32, 64);
    acc.z += __shfl_xor(acc.z, 32, 64); acc.w += __shfl_xor(acc.w, 32, 64);

    if (g == 0) {
        float di = dinv[i];
        float4 bl = *(const float4*)(b + l * 4);
        int grp = seg[i];
        float* pp = pooled + (size_t)grp * D + l * 4;
        atomicAdd(pp + 0, fmaf(acc.x, di, bl.x));
        atomicAdd(pp + 1, fmaf(acc.y, di, bl.y));
        atomicAdd(pp + 2, fmaf(acc.z, di, bl.z));
        atomicAdd(pp + 3, fmaf(acc.w, di, bl.w));
    }
}

__global__ void k_counts(const int* __restrict__ seg, float* __restrict__ counts) {
    int i = blockIdx.x * blockDim.x + threadIdx.x;
    if (i < N_NODES) atomicAdd(&counts[seg[i]], 1.0f);
}

// ---------------- head ----------------
__global__ void k_out(const float* __restrict__ pooled, const float* __restrict__ counts,
                      const float* __restrict__ Wout, const float* __restrict__ bout,
                      float* __restrict__ out) {
    __shared__ float prow[D];
    int g = blockIdx.x;
    int t = threadIdx.x;
    if (t < D) prow[t] = pooled[(size_t)g * D + t] / fmaxf(counts[g], 1.0f);
    __syncthreads();
    if (t < N_TARGETS) {
        float acc = bout[t];
#pragma unroll
        for (int k = 0; k < D; ++k)
            acc = fmaf(prow[k], Wout[k * N_TARGETS + t], acc);
        out[g * N_TARGETS + t] = acc;
    }
}

// ---------------- driver ----------------

extern "C" void kernel_launch(void* const* d_in, const int* in_sizes, int n_in,
                              void* d_out, int out_size, void* d_ws, size_t ws_size,
                              hipStream_t stream) {
    const float* x    = (const float*)d_in[0];
    const float* W1   = (const float*)d_in[1];
    const float* b1   = (const float*)d_in[2];
    const float* W2   = (const float*)d_in[3];
    const float* b2   = (const float*)d_in[4];
    const float* W3   = (const float*)d_in[5];
    const float* b3   = (const float*)d_in[6];
    const float* Wout = (const float*)d_in[7];
    const float* bout = (const float*)d_in[8];
    const int*   eidx = (const int*)d_in[9];
    const int*   seg  = (const int*)d_in[10];
    const int* src = eidx;
    const int* dst = eidx + N_EDGES;
    float* out = (float*)d_out;

    // workspace (~59MB). ebuck aliases bufB (dead until first pull).
    float*    bufA   = (float*)d_ws;                        // 6,400,000
    float*    bufB   = bufA + (size_t)N_NODES * D;          // 6,400,000
    unsigned* ebuck  = (unsigned*)bufB;                     // alias (1,600,000)
    int*      esrc   = (int*)(bufB + (size_t)N_NODES * D);  // 1,600,000
    float*    dinv   = (float*)(esrc + N_EDGES);            // 100,000
    int*      deg    = (int*)(dinv + N_NODES);              // 100,000
    int*      base   = deg + N_NODES;                       // 100,001 (+pad)
    int*      bsum   = base + N_NODES + 3;                  // 392
    int*      gcur   = bsum + NBUCK + 1;                    // 391 (+pad)
    float*    pooled = (float*)(gcur + NBUCK + 1);          // 32,768
    float*    counts = pooled + N_GRAPHS * D;               // 512

    const int NB = (N_NODES + 255) / 256;  // 391

    // ---- CSR build ----
    k_zero_i<<<NB, 256, 0, stream>>>(deg, N_NODES);
    k_deg<<<N_EDGES / 256, 256, 0, stream>>>(dst, deg);
    k_dinv<<<NB, 256, 0, stream>>>(deg, dinv);
    k_bsum<<<NBUCK, 256, 0, stream>>>(deg, bsum);
    k_scan2<<<1, 512, 0, stream>>>(bsum, gcur);
    k_part<<<256, 256, 0, stream>>>(src, dst, gcur, ebuck);
    k_fill2<<<NBUCK, 256, 0, stream>>>(ebuck, deg, bsum, base, esrc);

    // ---- 3 GCN layers ----
    const int MMB = (N_NODES + 63) / 64;  // 1563
    k_mm<<<MMB, 256, 0, stream>>>(x, W1, dinv, bufA, 0);
    k_pull<<<N_NODES / 4, 256, 0, stream>>>(bufA, esrc, base, dinv, b1, bufB);
    k_mm<<<MMB, 256, 0, stream>>>(bufB, W2, dinv, bufA, 1);
    k_pull<<<N_NODES / 4, 256, 0, stream>>>(bufA, esrc, base, dinv, b2, bufB);
    k_mm<<<MMB, 256, 0, stream>>>(bufB, W3, dinv, bufA, 1);

    // ---- layer-3 pull fused with mean-pool ----
    k_zero_f<<<(N_GRAPHS * D + N_GRAPHS + 255) / 256, 256, 0, stream>>>(pooled, N_GRAPHS * D + N_GRAPHS);
    k_counts<<<NB, 256, 0, stream>>>(seg, counts);
    k_pull_pool<<<N_NODES / 4, 256, 0, stream>>>(bufA, esrc, base, dinv, b3, seg, pooled);

    k_out<<<N_GRAPHS, 128, 0, stream>>>(pooled, counts, Wout, bout, out);
}

// Round 5
// 821.619 us; speedup vs baseline: 1.2647x; 1.2647x over previous
//
#include <hip/hip_runtime.h>

#define N_NODES   100000
#define N_EDGES   1600000
#define D         64
#define N_TARGETS 100
#define N_GRAPHS  512

// ---------------- utility ----------------

__global__ void k_zero_i(int* __restrict__ p, int n) {
    int i = blockIdx.x * blockDim.x + threadIdx.x;
    if (i < n) p[i] = 0;
}
__global__ void k_zero_f(float* __restrict__ p, int n) {
    int i = blockIdx.x * blockDim.x + threadIdx.x;
    if (i < n) p[i] = 0.0f;
}

// ---------------- CSR build (R3 scheme: simple scatter fill) ----------------

__global__ void k_deg(const int* __restrict__ dst, int* __restrict__ deg) {
    int e = blockIdx.x * blockDim.x + threadIdx.x;
    if (e < N_EDGES) atomicAdd(&deg[dst[e]], 1);
}

__global__ void k_dinv(const int* __restrict__ deg, float* __restrict__ dinv) {
    int i = blockIdx.x * blockDim.x + threadIdx.x;
    if (i < N_NODES) dinv[i] = rsqrtf((float)deg[i] + 1.0f);  // +1 self-loop
}

// exclusive scan of deg within each 256-block; block totals -> bsum
__global__ void k_scan1(const int* __restrict__ deg, int* __restrict__ base,
                        int* __restrict__ bsum) {
    __shared__ int s[256];
    int t = threadIdx.x, i = blockIdx.x * 256 + t;
    int v = (i < N_NODES) ? deg[i] : 0;
    s[t] = v;
    __syncthreads();
    for (int off = 1; off < 256; off <<= 1) {
        int x = (t >= off) ? s[t - off] : 0;
        __syncthreads();
        s[t] += x;
        __syncthreads();
    }
    if (i < N_NODES) base[i] = s[t] - v;      // exclusive within block
    if (t == 255) bsum[blockIdx.x] = s[255];  // block total
}

// exclusive scan of block sums (single block, 512 threads >= 391 blocks)
__global__ void k_scan2(int* __restrict__ bsum, int nb) {
    __shared__ int s[512];
    int t = threadIdx.x;
    int v = (t < nb) ? bsum[t] : 0;
    s[t] = v;
    __syncthreads();
    for (int off = 1; off < 512; off <<= 1) {
        int x = (t >= off) ? s[t - off] : 0;
        __syncthreads();
        s[t] += x;
        __syncthreads();
    }
    if (t < nb) bsum[t] = s[t] - v;
}

// add block offsets; zero cursor (reuses deg buffer); set base[N]=E
__global__ void k_scan3(int* __restrict__ base, const int* __restrict__ bsum,
                        int* __restrict__ cursor) {
    int i = blockIdx.x * blockDim.x + threadIdx.x;
    if (i < N_NODES) {
        base[i] += bsum[i >> 8];
        cursor[i] = 0;
    }
    if (i == 0) base[N_NODES] = N_EDGES;
}

__global__ void k_fill(const int* __restrict__ src, const int* __restrict__ dst,
                       const int* __restrict__ base, int* __restrict__ cursor,
                       int* __restrict__ esrc) {
    int e = blockIdx.x * blockDim.x + threadIdx.x;
    if (e < N_EDGES) {
        int d = dst[e];
        int pos = base[d] + atomicAdd(&cursor[d], 1);
        esrc[pos] = src[e];
    }
}

// ---------------- matmul: Y[row] = (relu?)X[row] @ W * dinv[row] ----------------
__global__ void __launch_bounds__(256)
k_mm(const float* __restrict__ X, const float* __restrict__ W,
     const float* __restrict__ dinv, float* __restrict__ Y, int relu) {
    __shared__ float Xs[64][68];
    __shared__ float Ws[64][68];
    int tid = threadIdx.x;
    int r0  = blockIdx.x * 64;
    {
        int lr = tid >> 4;
        int lc = (tid & 15) * 4;
#pragma unroll
        for (int i = 0; i < 4; ++i) {
            int row = lr + 16 * i;
            *(float4*)&Ws[row][lc] = *(const float4*)(W + row * 64 + lc);
            int gr = r0 + row;
            if (gr < N_NODES) {
                float4 xv = *(const float4*)(X + (size_t)gr * 64 + lc);
                if (relu) {
                    xv.x = fmaxf(xv.x, 0.0f); xv.y = fmaxf(xv.y, 0.0f);
                    xv.z = fmaxf(xv.z, 0.0f); xv.w = fmaxf(xv.w, 0.0f);
                }
                *(float4*)&Xs[row][lc] = xv;
            }
        }
    }
    __syncthreads();

    int tx = (tid & 15) * 4;
    int ty = (tid >> 4) * 4;
    float acc[4][4] = {{0.f}};

#pragma unroll
    for (int kk = 0; kk < 16; ++kk) {
        float4 a[4], w[4];
#pragma unroll
        for (int r = 0; r < 4; ++r) a[r] = *(float4*)&Xs[ty + r][kk * 4];
#pragma unroll
        for (int k = 0; k < 4; ++k) w[k] = *(float4*)&Ws[kk * 4 + k][tx];
#pragma unroll
        for (int r = 0; r < 4; ++r) {
#pragma unroll
            for (int k = 0; k < 4; ++k) {
                float av = ((const float*)&a[r])[k];
                acc[r][0] = fmaf(av, w[k].x, acc[r][0]);
                acc[r][1] = fmaf(av, w[k].y, acc[r][1]);
                acc[r][2] = fmaf(av, w[k].z, acc[r][2]);
                acc[r][3] = fmaf(av, w[k].w, acc[r][3]);
            }
        }
    }

#pragma unroll
    for (int r = 0; r < 4; ++r) {
        int gr = r0 + ty + r;
        if (gr < N_NODES) {
            float di = dinv[gr];
            float4 o = { acc[r][0] * di, acc[r][1] * di, acc[r][2] * di, acc[r][3] * di };
            *(float4*)(Y + (size_t)gr * 64 + tx) = o;
        }
    }
}

// ---------------- pull aggregation (float4-lane, 4-deep MLP) ----------------
// Wave = node. lane = 16*g + l: slot g handles edges {j+g, j+4+g, j+8+g, j+12+g};
// lane-part l holds features [4l,4l+4). 4 independent dwordx4 gathers (4KB) in
// flight per wave per step. Cross-slot sum via shfl_xor at the end.
__global__ void __launch_bounds__(256)
k_pull(const float* __restrict__ H, const int* __restrict__ esrc,
       const int* __restrict__ base, const float* __restrict__ dinv,
       const float* __restrict__ b, float* __restrict__ AGG) {
    int i    = blockIdx.x * 4 + (threadIdx.x >> 6);
    int lane = threadIdx.x & 63;
    int g = lane >> 4, l = lane & 15;
    int s0 = base[i], s1 = base[i + 1];
    float4 acc = {0.f, 0.f, 0.f, 0.f};
    if (g == 0) acc = *(const float4*)(H + (size_t)i * D + l * 4);  // self term

    int p = s0;
    while (p < s1) {
        int cnt = s1 - p;
        if (cnt > 64) cnt = 64;
        int ed = (lane < cnt) ? esrc[p + lane] : 0;
        int j = 0;
        for (; j + 16 <= cnt; j += 16) {
            int e0 = __shfl(ed, j + g, 64);
            int e1 = __shfl(ed, j + 4 + g, 64);
            int e2 = __shfl(ed, j + 8 + g, 64);
            int e3 = __shfl(ed, j + 12 + g, 64);
            float4 v0 = *(const float4*)(H + (size_t)e0 * D + l * 4);
            float4 v1 = *(const float4*)(H + (size_t)e1 * D + l * 4);
            float4 v2 = *(const float4*)(H + (size_t)e2 * D + l * 4);
            float4 v3 = *(const float4*)(H + (size_t)e3 * D + l * 4);
            acc.x += (v0.x + v1.x) + (v2.x + v3.x);
            acc.y += (v0.y + v1.y) + (v2.y + v3.y);
            acc.z += (v0.z + v1.z) + (v2.z + v3.z);
            acc.w += (v0.w + v1.w) + (v2.w + v3.w);
        }
        for (; j < cnt; j += 4) {
            int idx = j + g;
            int e0 = __shfl(ed, idx & 63, 64);
            if (idx < cnt) {
                float4 v0 = *(const float4*)(H + (size_t)e0 * D + l * 4);
                acc.x += v0.x; acc.y += v0.y; acc.z += v0.z; acc.w += v0.w;
            }
        }
        p += cnt;
    }
    acc.x += __shfl_xor(acc.x, 16, 64); acc.y += __shfl_xor(acc.y, 16, 64);
    acc.z += __shfl_xor(acc.z, 16, 64); acc.w += __shfl_xor(acc.w, 16, 64);
    acc.x += __shfl_xor(acc.x, 32, 64); acc.y += __shfl_xor(acc.y, 32, 64);
    acc.z += __shfl_xor(acc.z, 32, 64); acc.w += __shfl_xor(acc.w, 32, 64);

    if (g == 0) {
        float di = dinv[i];
        float4 bl = *(const float4*)(b + l * 4);
        float4 o = { fmaf(acc.x, di, bl.x), fmaf(acc.y, di, bl.y),
                     fmaf(acc.z, di, bl.z), fmaf(acc.w, di, bl.w) };
        *(float4*)(AGG + (size_t)i * D + l * 4) = o;
    }
}

// layer-3 variant: fused graph mean-pool accumulation
__global__ void __launch_bounds__(256)
k_pull_pool(const float* __restrict__ H, const int* __restrict__ esrc,
            const int* __restrict__ base, const float* __restrict__ dinv,
            const float* __restrict__ b, const int* __restrict__ seg,
            float* __restrict__ pooled) {
    int i    = blockIdx.x * 4 + (threadIdx.x >> 6);
    int lane = threadIdx.x & 63;
    int g = lane >> 4, l = lane & 15;
    int s0 = base[i], s1 = base[i + 1];
    float4 acc = {0.f, 0.f, 0.f, 0.f};
    if (g == 0) acc = *(const float4*)(H + (size_t)i * D + l * 4);

    int p = s0;
    while (p < s1) {
        int cnt = s1 - p;
        if (cnt > 64) cnt = 64;
        int ed = (lane < cnt) ? esrc[p + lane] : 0;
        int j = 0;
        for (; j + 16 <= cnt; j += 16) {
            int e0 = __shfl(ed, j + g, 64);
            int e1 = __shfl(ed, j + 4 + g, 64);
            int e2 = __shfl(ed, j + 8 + g, 64);
            int e3 = __shfl(ed, j + 12 + g, 64);
            float4 v0 = *(const float4*)(H + (size_t)e0 * D + l * 4);
            float4 v1 = *(const float4*)(H + (size_t)e1 * D + l * 4);
            float4 v2 = *(const float4*)(H + (size_t)e2 * D + l * 4);
            float4 v3 = *(const float4*)(H + (size_t)e3 * D + l * 4);
            acc.x += (v0.x + v1.x) + (v2.x + v3.x);
            acc.y += (v0.y + v1.y) + (v2.y + v3.y);
            acc.z += (v0.z + v1.z) + (v2.z + v3.z);
            acc.w += (v0.w + v1.w) + (v2.w + v3.w);
        }
        for (; j < cnt; j += 4) {
            int idx = j + g;
            int e0 = __shfl(ed, idx & 63, 64);
            if (idx < cnt) {
                float4 v0 = *(const float4*)(H + (size_t)e0 * D + l * 4);
                acc.x += v0.x; acc.y += v0.y; acc.z += v0.z; acc.w += v0.w;
            }
        }
        p += cnt;
    }
    acc.x += __shfl_xor(acc.x, 16, 64); acc.y += __shfl_xor(acc.y, 16, 64);
    acc.z += __shfl_xor(acc.z, 16, 64); acc.w += __shfl_xor(acc.w, 16, 64);
    acc.x += __shfl_xor(acc.x, 32, 64); acc.y += __shfl_xor(acc.y, 32, 64);
    acc.z += __shfl_xor(acc.z, 32, 64); acc.w += __shfl_xor(acc.w, 32, 64);

    if (g == 0) {
        float di = dinv[i];
        float4 bl = *(const float4*)(b + l * 4);
        int grp = seg[i];
        float* pp = pooled + (size_t)grp * D + l * 4;
        atomicAdd(pp + 0, fmaf(acc.x, di, bl.x));
        atomicAdd(pp + 1, fmaf(acc.y, di, bl.y));
        atomicAdd(pp + 2, fmaf(acc.z, di, bl.z));
        atomicAdd(pp + 3, fmaf(acc.w, di, bl.w));
    }
}

__global__ void k_counts(const int* __restrict__ seg, float* __restrict__ counts) {
    int i = blockIdx.x * blockDim.x + threadIdx.x;
    if (i < N_NODES) atomicAdd(&counts[seg[i]], 1.0f);
}

// ---------------- head ----------------
__global__ void k_out(const float* __restrict__ pooled, const float* __restrict__ counts,
                      const float* __restrict__ Wout, const float* __restrict__ bout,
                      float* __restrict__ out) {
    __shared__ float prow[D];
    int g = blockIdx.x;
    int t = threadIdx.x;
    if (t < D) prow[t] = pooled[(size_t)g * D + t] / fmaxf(counts[g], 1.0f);
    __syncthreads();
    if (t < N_TARGETS) {
        float acc = bout[t];
#pragma unroll
        for (int k = 0; k < D; ++k)
            acc = fmaf(prow[k], Wout[k * N_TARGETS + t], acc);
        out[g * N_TARGETS + t] = acc;
    }
}

// ---------------- driver ----------------

extern "C" void kernel_launch(void* const* d_in, const int* in_sizes, int n_in,
                              void* d_out, int out_size, void* d_ws, size_t ws_size,
                              hipStream_t stream) {
    const float* x    = (const float*)d_in[0];
    const float* W1   = (const float*)d_in[1];
    const float* b1   = (const float*)d_in[2];
    const float* W2   = (const float*)d_in[3];
    const float* b2   = (const float*)d_in[4];
    const float* W3   = (const float*)d_in[5];
    const float* b3   = (const float*)d_in[6];
    const float* Wout = (const float*)d_in[7];
    const float* bout = (const float*)d_in[8];
    const int*   eidx = (const int*)d_in[9];
    const int*   seg  = (const int*)d_in[10];
    const int* src = eidx;
    const int* dst = eidx + N_EDGES;
    float* out = (float*)d_out;

    // workspace layout (all 4B elems): total ~59 MB
    float* bufA   = (float*)d_ws;                  // 6,400,000
    float* bufB   = bufA + (size_t)N_NODES * D;    // 6,400,000
    int*   esrc   = (int*)(bufB + (size_t)N_NODES * D);  // 1,600,000
    float* dinv   = (float*)(esrc + N_EDGES);      // 100,000
    int*   degc   = (int*)(dinv + N_NODES);        // 100,000 (deg, then cursor)
    int*   base   = degc + N_NODES;                // 100,001 (+pad)
    int*   bsum   = base + N_NODES + 4;            // 512
    float* pooled = (float*)(bsum + 512);          // 32,768
    float* counts = pooled + N_GRAPHS * D;         // 512

    const int NB = (N_NODES + 255) / 256;  // 391

    // ---- CSR build ----
    k_zero_i<<<NB, 256, 0, stream>>>(degc, N_NODES);
    k_deg<<<N_EDGES / 256, 256, 0, stream>>>(dst, degc);
    k_dinv<<<NB, 256, 0, stream>>>(degc, dinv);
    k_scan1<<<NB, 256, 0, stream>>>(degc, base, bsum);
    k_scan2<<<1, 512, 0, stream>>>(bsum, NB);
    k_scan3<<<NB, 256, 0, stream>>>(base, bsum, degc);
    k_fill<<<N_EDGES / 256, 256, 0, stream>>>(src, dst, base, degc, esrc);

    // ---- 3 GCN layers ----
    const int MMB = (N_NODES + 63) / 64;  // 1563
    k_mm<<<MMB, 256, 0, stream>>>(x, W1, dinv, bufA, 0);
    k_pull<<<N_NODES / 4, 256, 0, stream>>>(bufA, esrc, base, dinv, b1, bufB);
    k_mm<<<MMB, 256, 0, stream>>>(bufB, W2, dinv, bufA, 1);
    k_pull<<<N_NODES / 4, 256, 0, stream>>>(bufA, esrc, base, dinv, b2, bufB);
    k_mm<<<MMB, 256, 0, stream>>>(bufB, W3, dinv, bufA, 1);

    // ---- layer-3 pull fused with mean-pool ----
    k_zero_f<<<(N_GRAPHS * D + N_GRAPHS + 255) / 256, 256, 0, stream>>>(pooled, N_GRAPHS * D + N_GRAPHS);
    k_counts<<<NB, 256, 0, stream>>>(seg, counts);
    k_pull_pool<<<N_NODES / 4, 256, 0, stream>>>(bufA, esrc, base, dinv, b3, seg, pooled);

    k_out<<<N_GRAPHS, 128, 0, stream>>>(pooled, counts, Wout, bout, out);
}

// Round 6
// 645.290 us; speedup vs baseline: 1.6103x; 1.2733x over previous
//
#include <hip/hip_runtime.h>

#define N_NODES   100000
#define N_EDGES   1600000
#define D         64
#define N_TARGETS 100
#define N_GRAPHS  512

typedef _Float16 half4 __attribute__((ext_vector_type(4)));

// ---------------- utility ----------------

__global__ void k_zero_i(int* __restrict__ p, int n) {
    int i = blockIdx.x * blockDim.x + threadIdx.x;
    if (i < n) p[i] = 0;
}
__global__ void k_zero_f(float* __restrict__ p, int n) {
    int i = blockIdx.x * blockDim.x + threadIdx.x;
    if (i < n) p[i] = 0.0f;
}

// ---------------- CSR build ----------------

__global__ void k_deg(const int* __restrict__ dst, int* __restrict__ deg) {
    int e = blockIdx.x * blockDim.x + threadIdx.x;
    if (e < N_EDGES) atomicAdd(&deg[dst[e]], 1);
}

__global__ void k_dinv(const int* __restrict__ deg, float* __restrict__ dinv) {
    int i = blockIdx.x * blockDim.x + threadIdx.x;
    if (i < N_NODES) dinv[i] = rsqrtf((float)deg[i] + 1.0f);  // +1 self-loop
}

__global__ void k_scan1(const int* __restrict__ deg, int* __restrict__ base,
                        int* __restrict__ bsum) {
    __shared__ int s[256];
    int t = threadIdx.x, i = blockIdx.x * 256 + t;
    int v = (i < N_NODES) ? deg[i] : 0;
    s[t] = v;
    __syncthreads();
    for (int off = 1; off < 256; off <<= 1) {
        int x = (t >= off) ? s[t - off] : 0;
        __syncthreads();
        s[t] += x;
        __syncthreads();
    }
    if (i < N_NODES) base[i] = s[t] - v;
    if (t == 255) bsum[blockIdx.x] = s[255];
}

__global__ void k_scan2(int* __restrict__ bsum, int nb) {
    __shared__ int s[512];
    int t = threadIdx.x;
    int v = (t < nb) ? bsum[t] : 0;
    s[t] = v;
    __syncthreads();
    for (int off = 1; off < 512; off <<= 1) {
        int x = (t >= off) ? s[t - off] : 0;
        __syncthreads();
        s[t] += x;
        __syncthreads();
    }
    if (t < nb) bsum[t] = s[t] - v;
}

__global__ void k_scan3(int* __restrict__ base, const int* __restrict__ bsum,
                        int* __restrict__ cursor) {
    int i = blockIdx.x * blockDim.x + threadIdx.x;
    if (i < N_NODES) {
        base[i] += bsum[i >> 8];
        cursor[i] = 0;
    }
    if (i == 0) base[N_NODES] = N_EDGES;
}

__global__ void k_fill(const int* __restrict__ src, const int* __restrict__ dst,
                       const int* __restrict__ base, int* __restrict__ cursor,
                       int* __restrict__ esrc) {
    int e = blockIdx.x * blockDim.x + threadIdx.x;
    if (e < N_EDGES) {
        int d = dst[e];
        int pos = base[d] + atomicAdd(&cursor[d], 1);
        esrc[pos] = src[e];
    }
}

// ------ matmul: H16[row] = fp16( (relu?)X[row] @ W * dinv[row] ) ------
__global__ void __launch_bounds__(256)
k_mm(const float* __restrict__ X, const float* __restrict__ W,
     const float* __restrict__ dinv, _Float16* __restrict__ Y16, int relu) {
    __shared__ float Xs[64][68];
    __shared__ float Ws[64][68];
    int tid = threadIdx.x;
    int r0  = blockIdx.x * 64;
    {
        int lr = tid >> 4;
        int lc = (tid & 15) * 4;
#pragma unroll
        for (int i = 0; i < 4; ++i) {
            int row = lr + 16 * i;
            *(float4*)&Ws[row][lc] = *(const float4*)(W + row * 64 + lc);
            int gr = r0 + row;
            if (gr < N_NODES) {
                float4 xv = *(const float4*)(X + (size_t)gr * 64 + lc);
                if (relu) {
                    xv.x = fmaxf(xv.x, 0.0f); xv.y = fmaxf(xv.y, 0.0f);
                    xv.z = fmaxf(xv.z, 0.0f); xv.w = fmaxf(xv.w, 0.0f);
                }
                *(float4*)&Xs[row][lc] = xv;
            }
        }
    }
    __syncthreads();

    int tx = (tid & 15) * 4;
    int ty = (tid >> 4) * 4;
    float acc[4][4] = {{0.f}};

#pragma unroll
    for (int kk = 0; kk < 16; ++kk) {
        float4 a[4], w[4];
#pragma unroll
        for (int r = 0; r < 4; ++r) a[r] = *(float4*)&Xs[ty + r][kk * 4];
#pragma unroll
        for (int k = 0; k < 4; ++k) w[k] = *(float4*)&Ws[kk * 4 + k][tx];
#pragma unroll
        for (int r = 0; r < 4; ++r) {
#pragma unroll
            for (int k = 0; k < 4; ++k) {
                float av = ((const float*)&a[r])[k];
                acc[r][0] = fmaf(av, w[k].x, acc[r][0]);
                acc[r][1] = fmaf(av, w[k].y, acc[r][1]);
                acc[r][2] = fmaf(av, w[k].z, acc[r][2]);
                acc[r][3] = fmaf(av, w[k].w, acc[r][3]);
            }
        }
    }

#pragma unroll
    for (int r = 0; r < 4; ++r) {
        int gr = r0 + ty + r;
        if (gr < N_NODES) {
            float di = dinv[gr];
            half4 o;
            o.x = (_Float16)(acc[r][0] * di);
            o.y = (_Float16)(acc[r][1] * di);
            o.z = (_Float16)(acc[r][2] * di);
            o.w = (_Float16)(acc[r][3] * di);
            *(half4*)(Y16 + (size_t)gr * 64 + tx) = o;
        }
    }
}

// ---------------- pull aggregation (fp16 gathers, fp32 accumulate) --------
// Wave = node. lane = 16*g + l: slot g handles edges j+g, j+4+g, ...;
// lane-part l holds features [4l,4l+4) (8B half4 loads). Cross-slot shfl_xor.
__global__ void __launch_bounds__(256)
k_pull(const _Float16* __restrict__ H, const int* __restrict__ esrc,
       const int* __restrict__ base, const float* __restrict__ dinv,
       const float* __restrict__ b, float* __restrict__ AGG) {
    int i    = blockIdx.x * 4 + (threadIdx.x >> 6);
    int lane = threadIdx.x & 63;
    int g = lane >> 4, l = lane & 15;
    int s0 = base[i], s1 = base[i + 1];
    float4 acc = {0.f, 0.f, 0.f, 0.f};
    if (g == 0) {  // self term (pre-scaled by dinv_i)
        half4 sv = *(const half4*)(H + (size_t)i * D + l * 4);
        acc.x = (float)sv.x; acc.y = (float)sv.y;
        acc.z = (float)sv.z; acc.w = (float)sv.w;
    }

    int p = s0;
    while (p < s1) {
        int cnt = s1 - p;
        if (cnt > 64) cnt = 64;
        int ed = (lane < cnt) ? esrc[p + lane] : 0;
        int j = 0;
        for (; j + 16 <= cnt; j += 16) {
            int e0 = __shfl(ed, j + g, 64);
            int e1 = __shfl(ed, j + 4 + g, 64);
            int e2 = __shfl(ed, j + 8 + g, 64);
            int e3 = __shfl(ed, j + 12 + g, 64);
            half4 v0 = *(const half4*)(H + (size_t)e0 * D + l * 4);
            half4 v1 = *(const half4*)(H + (size_t)e1 * D + l * 4);
            half4 v2 = *(const half4*)(H + (size_t)e2 * D + l * 4);
            half4 v3 = *(const half4*)(H + (size_t)e3 * D + l * 4);
            acc.x += ((float)v0.x + (float)v1.x) + ((float)v2.x + (float)v3.x);
            acc.y += ((float)v0.y + (float)v1.y) + ((float)v2.y + (float)v3.y);
            acc.z += ((float)v0.z + (float)v1.z) + ((float)v2.z + (float)v3.z);
            acc.w += ((float)v0.w + (float)v1.w) + ((float)v2.w + (float)v3.w);
        }
        for (; j + 8 <= cnt; j += 8) {
            int e0 = __shfl(ed, j + g, 64);
            int e1 = __shfl(ed, j + 4 + g, 64);
            half4 v0 = *(const half4*)(H + (size_t)e0 * D + l * 4);
            half4 v1 = *(const half4*)(H + (size_t)e1 * D + l * 4);
            acc.x += (float)v0.x + (float)v1.x;
            acc.y += (float)v0.y + (float)v1.y;
            acc.z += (float)v0.z + (float)v1.z;
            acc.w += (float)v0.w + (float)v1.w;
        }
        for (; j < cnt; j += 4) {
            int idx = j + g;
            int e0 = __shfl(ed, idx & 63, 64);
            if (idx < cnt) {
                half4 v0 = *(const half4*)(H + (size_t)e0 * D + l * 4);
                acc.x += (float)v0.x; acc.y += (float)v0.y;
                acc.z += (float)v0.z; acc.w += (float)v0.w;
            }
        }
        p += cnt;
    }
    acc.x += __shfl_xor(acc.x, 16, 64); acc.y += __shfl_xor(acc.y, 16, 64);
    acc.z += __shfl_xor(acc.z, 16, 64); acc.w += __shfl_xor(acc.w, 16, 64);
    acc.x += __shfl_xor(acc.x, 32, 64); acc.y += __shfl_xor(acc.y, 32, 64);
    acc.z += __shfl_xor(acc.z, 32, 64); acc.w += __shfl_xor(acc.w, 32, 64);

    if (g == 0) {
        float di = dinv[i];
        float4 bl = *(const float4*)(b + l * 4);
        float4 o = { fmaf(acc.x, di, bl.x), fmaf(acc.y, di, bl.y),
                     fmaf(acc.z, di, bl.z), fmaf(acc.w, di, bl.w) };
        *(float4*)(AGG + (size_t)i * D + l * 4) = o;
    }
}

// ---- segment-sorted pooling: register accumulate, atomic flush on boundary ----
// batch_seg is sorted; each wave walks 64 consecutive nodes (lane = feature),
// flushes once per segment boundary (~0.3 per wave) + once at the end.
__global__ void __launch_bounds__(256)
k_pool_seg(const float* __restrict__ H, const int* __restrict__ seg,
           float* __restrict__ pooled) {
    int wave = threadIdx.x >> 6;
    int lane = threadIdx.x & 63;
    int n0 = (blockIdx.x * 4 + wave) * 64;
    if (n0 >= N_NODES) return;
    int nEnd = n0 + 64;
    if (nEnd > N_NODES) nEnd = N_NODES;
    int cur = seg[n0];
    float acc = 0.0f;
    for (int n = n0; n < nEnd; ++n) {
        int gsg = seg[n];  // wave-uniform
        if (gsg != cur) {
            atomicAdd(&pooled[(size_t)cur * D + lane], acc);
            acc = 0.0f;
            cur = gsg;
        }
        acc += H[(size_t)n * D + lane];
    }
    atomicAdd(&pooled[(size_t)cur * D + lane], acc);
}

__global__ void k_counts(const int* __restrict__ seg, float* __restrict__ counts) {
    int i = blockIdx.x * blockDim.x + threadIdx.x;
    if (i < N_NODES) atomicAdd(&counts[seg[i]], 1.0f);
}

// ---------------- head ----------------
__global__ void k_out(const float* __restrict__ pooled, const float* __restrict__ counts,
                      const float* __restrict__ Wout, const float* __restrict__ bout,
                      float* __restrict__ out) {
    __shared__ float prow[D];
    int g = blockIdx.x;
    int t = threadIdx.x;
    if (t < D) prow[t] = pooled[(size_t)g * D + t] / fmaxf(counts[g], 1.0f);
    __syncthreads();
    if (t < N_TARGETS) {
        float acc = bout[t];
#pragma unroll
        for (int k = 0; k < D; ++k)
            acc = fmaf(prow[k], Wout[k * N_TARGETS + t], acc);
        out[g * N_TARGETS + t] = acc;
    }
}

// ---------------- driver ----------------

extern "C" void kernel_launch(void* const* d_in, const int* in_sizes, int n_in,
                              void* d_out, int out_size, void* d_ws, size_t ws_size,
                              hipStream_t stream) {
    const float* x    = (const float*)d_in[0];
    const float* W1   = (const float*)d_in[1];
    const float* b1   = (const float*)d_in[2];
    const float* W2   = (const float*)d_in[3];
    const float* b2   = (const float*)d_in[4];
    const float* W3   = (const float*)d_in[5];
    const float* b3   = (const float*)d_in[6];
    const float* Wout = (const float*)d_in[7];
    const float* bout = (const float*)d_in[8];
    const int*   eidx = (const int*)d_in[9];
    const int*   seg  = (const int*)d_in[10];
    const int* src = eidx;
    const int* dst = eidx + N_EDGES;
    float* out = (float*)d_out;

    // workspace layout (~47 MB)
    _Float16* H16    = (_Float16*)d_ws;                      // 6,400,000 halfs (12.8MB)
    float*    bufB   = (float*)(H16 + (size_t)N_NODES * D);  // 6,400,000 floats (AGG)
    int*      esrc   = (int*)(bufB + (size_t)N_NODES * D);   // 1,600,000
    float*    dinv   = (float*)(esrc + N_EDGES);             // 100,000
    int*      degc   = (int*)(dinv + N_NODES);               // 100,000
    int*      base   = degc + N_NODES;                       // 100,001 (+pad)
    int*      bsum   = base + N_NODES + 4;                   // 512
    float*    pooled = (float*)(bsum + 512);                 // 32,768
    float*    counts = pooled + N_GRAPHS * D;                // 512

    const int NB = (N_NODES + 255) / 256;  // 391

    // ---- CSR build ----
    k_zero_i<<<NB, 256, 0, stream>>>(degc, N_NODES);
    k_deg<<<N_EDGES / 256, 256, 0, stream>>>(dst, degc);
    k_dinv<<<NB, 256, 0, stream>>>(degc, dinv);
    k_scan1<<<NB, 256, 0, stream>>>(degc, base, bsum);
    k_scan2<<<1, 512, 0, stream>>>(bsum, NB);
    k_scan3<<<NB, 256, 0, stream>>>(base, bsum, degc);
    k_fill<<<N_EDGES / 256, 256, 0, stream>>>(src, dst, base, degc, esrc);

    // ---- 3 GCN layers ----
    const int MMB = (N_NODES + 63) / 64;  // 1563
    k_mm<<<MMB, 256, 0, stream>>>(x, W1, dinv, H16, 0);
    k_pull<<<N_NODES / 4, 256, 0, stream>>>(H16, esrc, base, dinv, b1, bufB);
    k_mm<<<MMB, 256, 0, stream>>>(bufB, W2, dinv, H16, 1);
    k_pull<<<N_NODES / 4, 256, 0, stream>>>(H16, esrc, base, dinv, b2, bufB);
    k_mm<<<MMB, 256, 0, stream>>>(bufB, W3, dinv, H16, 1);
    k_pull<<<N_NODES / 4, 256, 0, stream>>>(H16, esrc, base, dinv, b3, bufB);

    // ---- mean pool (sorted-segment) + head ----
    k_zero_f<<<(N_GRAPHS * D + N_GRAPHS + 255) / 256, 256, 0, stream>>>(pooled, N_GRAPHS * D + N_GRAPHS);
    k_counts<<<NB, 256, 0, stream>>>(seg, counts);
    k_pool_seg<<<NB, 256, 0, stream>>>(bufB, seg, pooled);

    k_out<<<N_GRAPHS, 128, 0, stream>>>(pooled, counts, Wout, bout, out);
}

// Round 7
// 639.975 us; speedup vs baseline: 1.6237x; 1.0083x over previous
//
#include <hip/hip_runtime.h>

#define N_NODES   100000
#define N_EDGES   1600000
#define D         64
#define N_TARGETS 100
#define N_GRAPHS  512

typedef _Float16 half4 __attribute__((ext_vector_type(4)));
typedef _Float16 half8 __attribute__((ext_vector_type(8)));

// ---------------- utility ----------------

__global__ void k_zero_i(int* __restrict__ p, int n) {
    int i = blockIdx.x * blockDim.x + threadIdx.x;
    if (i < n) p[i] = 0;
}
__global__ void k_zero_f(float* __restrict__ p, int n) {
    int i = blockIdx.x * blockDim.x + threadIdx.x;
    if (i < n) p[i] = 0.0f;
}

// ---------------- CSR build ----------------

__global__ void k_deg(const int* __restrict__ dst, int* __restrict__ deg) {
    int e = blockIdx.x * blockDim.x + threadIdx.x;
    if (e < N_EDGES) atomicAdd(&deg[dst[e]], 1);
}

__global__ void k_dinv(const int* __restrict__ deg, float* __restrict__ dinv) {
    int i = blockIdx.x * blockDim.x + threadIdx.x;
    if (i < N_NODES) dinv[i] = rsqrtf((float)deg[i] + 1.0f);  // +1 self-loop
}

__global__ void k_scan1(const int* __restrict__ deg, int* __restrict__ base,
                        int* __restrict__ bsum) {
    __shared__ int s[256];
    int t = threadIdx.x, i = blockIdx.x * 256 + t;
    int v = (i < N_NODES) ? deg[i] : 0;
    s[t] = v;
    __syncthreads();
    for (int off = 1; off < 256; off <<= 1) {
        int x = (t >= off) ? s[t - off] : 0;
        __syncthreads();
        s[t] += x;
        __syncthreads();
    }
    if (i < N_NODES) base[i] = s[t] - v;
    if (t == 255) bsum[blockIdx.x] = s[255];
}

__global__ void k_scan2(int* __restrict__ bsum, int nb) {
    __shared__ int s[512];
    int t = threadIdx.x;
    int v = (t < nb) ? bsum[t] : 0;
    s[t] = v;
    __syncthreads();
    for (int off = 1; off < 512; off <<= 1) {
        int x = (t >= off) ? s[t - off] : 0;
        __syncthreads();
        s[t] += x;
        __syncthreads();
    }
    if (t < nb) bsum[t] = s[t] - v;
}

__global__ void k_scan3(int* __restrict__ base, const int* __restrict__ bsum,
                        int* __restrict__ cursor) {
    int i = blockIdx.x * blockDim.x + threadIdx.x;
    if (i < N_NODES) {
        base[i] += bsum[i >> 8];
        cursor[i] = 0;
    }
    if (i == 0) base[N_NODES] = N_EDGES;
}

__global__ void k_fill(const int* __restrict__ src, const int* __restrict__ dst,
                       const int* __restrict__ base, int* __restrict__ cursor,
                       int* __restrict__ esrc) {
    int e = blockIdx.x * blockDim.x + threadIdx.x;
    if (e < N_EDGES) {
        int d = dst[e];
        int pos = base[d] + atomicAdd(&cursor[d], 1);
        esrc[pos] = src[e];
    }
}

// ------ matmul: H16[row] = fp16( (relu?)X[row] @ W * dinv[row] ) ------
__global__ void __launch_bounds__(256)
k_mm(const float* __restrict__ X, const float* __restrict__ W,
     const float* __restrict__ dinv, _Float16* __restrict__ Y16, int relu) {
    __shared__ float Xs[64][68];
    __shared__ float Ws[64][68];
    int tid = threadIdx.x;
    int r0  = blockIdx.x * 64;
    {
        int lr = tid >> 4;
        int lc = (tid & 15) * 4;
#pragma unroll
        for (int i = 0; i < 4; ++i) {
            int row = lr + 16 * i;
            *(float4*)&Ws[row][lc] = *(const float4*)(W + row * 64 + lc);
            int gr = r0 + row;
            if (gr < N_NODES) {
                float4 xv = *(const float4*)(X + (size_t)gr * 64 + lc);
                if (relu) {
                    xv.x = fmaxf(xv.x, 0.0f); xv.y = fmaxf(xv.y, 0.0f);
                    xv.z = fmaxf(xv.z, 0.0f); xv.w = fmaxf(xv.w, 0.0f);
                }
                *(float4*)&Xs[row][lc] = xv;
            }
        }
    }
    __syncthreads();

    int tx = (tid & 15) * 4;
    int ty = (tid >> 4) * 4;
    float acc[4][4] = {{0.f}};

#pragma unroll
    for (int kk = 0; kk < 16; ++kk) {
        float4 a[4], w[4];
#pragma unroll
        for (int r = 0; r < 4; ++r) a[r] = *(float4*)&Xs[ty + r][kk * 4];
#pragma unroll
        for (int k = 0; k < 4; ++k) w[k] = *(float4*)&Ws[kk * 4 + k][tx];
#pragma unroll
        for (int r = 0; r < 4; ++r) {
#pragma unroll
            for (int k = 0; k < 4; ++k) {
                float av = ((const float*)&a[r])[k];
                acc[r][0] = fmaf(av, w[k].x, acc[r][0]);
                acc[r][1] = fmaf(av, w[k].y, acc[r][1]);
                acc[r][2] = fmaf(av, w[k].z, acc[r][2]);
                acc[r][3] = fmaf(av, w[k].w, acc[r][3]);
            }
        }
    }

#pragma unroll
    for (int r = 0; r < 4; ++r) {
        int gr = r0 + ty + r;
        if (gr < N_NODES) {
            float di = dinv[gr];
            half4 o;
            o.x = (_Float16)(acc[r][0] * di);
            o.y = (_Float16)(acc[r][1] * di);
            o.z = (_Float16)(acc[r][2] * di);
            o.w = (_Float16)(acc[r][3] * di);
            *(half4*)(Y16 + (size_t)gr * 64 + tx) = o;
        }
    }
}

// ---------------- pull aggregation (fp16 half8 gathers, fp32 accumulate) ----
// Wave = node. lane = 8*g + l: slot g in [0,8) handles edges j+g, j+8+g, ...;
// lane-part l in [0,8) holds features [8l,8l+8) as one 16B half8 load
// (global_load_dwordx4). 4 beats unrolled -> 32 edges / 4KB in flight per
// wave. Cross-slot reduction: shfl_xor 8/16/32.
__global__ void __launch_bounds__(256)
k_pull(const _Float16* __restrict__ H, const int* __restrict__ esrc,
       const int* __restrict__ base, const float* __restrict__ dinv,
       const float* __restrict__ b, float* __restrict__ AGG) {
    int i    = blockIdx.x * 4 + (threadIdx.x >> 6);
    int lane = threadIdx.x & 63;
    int g = lane >> 3, l = lane & 7;
    int s0 = base[i], s1 = base[i + 1];
    float acc[8] = {0.f, 0.f, 0.f, 0.f, 0.f, 0.f, 0.f, 0.f};
    if (g == 0) {  // self term (pre-scaled by dinv_i)
        half8 sv = *(const half8*)(H + (size_t)i * D + l * 8);
#pragma unroll
        for (int q = 0; q < 8; ++q) acc[q] = (float)sv[q];
    }

    int p = s0;
    while (p < s1) {
        int cnt = s1 - p;
        if (cnt > 64) cnt = 64;
        int ed = (lane < cnt) ? esrc[p + lane] : 0;
        int j = 0;
        for (; j + 32 <= cnt; j += 32) {
            int e0 = __shfl(ed, j + g, 64);
            int e1 = __shfl(ed, j + 8 + g, 64);
            int e2 = __shfl(ed, j + 16 + g, 64);
            int e3 = __shfl(ed, j + 24 + g, 64);
            half8 v0 = *(const half8*)(H + (size_t)e0 * D + l * 8);
            half8 v1 = *(const half8*)(H + (size_t)e1 * D + l * 8);
            half8 v2 = *(const half8*)(H + (size_t)e2 * D + l * 8);
            half8 v3 = *(const half8*)(H + (size_t)e3 * D + l * 8);
#pragma unroll
            for (int q = 0; q < 8; ++q)
                acc[q] += ((float)v0[q] + (float)v1[q]) + ((float)v2[q] + (float)v3[q]);
        }
        for (; j + 8 <= cnt; j += 8) {
            int e0 = __shfl(ed, j + g, 64);
            half8 v0 = *(const half8*)(H + (size_t)e0 * D + l * 8);
#pragma unroll
            for (int q = 0; q < 8; ++q) acc[q] += (float)v0[q];
        }
        if (j < cnt) {  // tail: < 8 edges
            int idx = j + g;
            int e0 = __shfl(ed, idx & 63, 64);
            if (idx < cnt) {
                half8 v0 = *(const half8*)(H + (size_t)e0 * D + l * 8);
#pragma unroll
                for (int q = 0; q < 8; ++q) acc[q] += (float)v0[q];
            }
        }
        p += cnt;
    }
#pragma unroll
    for (int off = 8; off <= 32; off <<= 1) {
#pragma unroll
        for (int q = 0; q < 8; ++q)
            acc[q] += __shfl_xor(acc[q], off, 64);
    }

    if (g == 0) {
        float di = dinv[i];
        float4 bl0 = *(const float4*)(b + l * 8);
        float4 bl1 = *(const float4*)(b + l * 8 + 4);
        float4 o0 = { fmaf(acc[0], di, bl0.x), fmaf(acc[1], di, bl0.y),
                      fmaf(acc[2], di, bl0.z), fmaf(acc[3], di, bl0.w) };
        float4 o1 = { fmaf(acc[4], di, bl1.x), fmaf(acc[5], di, bl1.y),
                      fmaf(acc[6], di, bl1.z), fmaf(acc[7], di, bl1.w) };
        *(float4*)(AGG + (size_t)i * D + l * 8)     = o0;
        *(float4*)(AGG + (size_t)i * D + l * 8 + 4) = o1;
    }
}

// ---- segment-sorted pooling: register accumulate, atomic flush on boundary ----
__global__ void __launch_bounds__(256)
k_pool_seg(const float* __restrict__ H, const int* __restrict__ seg,
           float* __restrict__ pooled) {
    int wave = threadIdx.x >> 6;
    int lane = threadIdx.x & 63;
    int n0 = (blockIdx.x * 4 + wave) * 64;
    if (n0 >= N_NODES) return;
    int nEnd = n0 + 64;
    if (nEnd > N_NODES) nEnd = N_NODES;
    int cur = seg[n0];
    float acc = 0.0f;
    for (int n = n0; n < nEnd; ++n) {
        int gsg = seg[n];  // wave-uniform
        if (gsg != cur) {
            atomicAdd(&pooled[(size_t)cur * D + lane], acc);
            acc = 0.0f;
            cur = gsg;
        }
        acc += H[(size_t)n * D + lane];
    }
    atomicAdd(&pooled[(size_t)cur * D + lane], acc);
}

__global__ void k_counts(const int* __restrict__ seg, float* __restrict__ counts) {
    int i = blockIdx.x * blockDim.x + threadIdx.x;
    if (i < N_NODES) atomicAdd(&counts[seg[i]], 1.0f);
}

// ---------------- head ----------------
__global__ void k_out(const float* __restrict__ pooled, const float* __restrict__ counts,
                      const float* __restrict__ Wout, const float* __restrict__ bout,
                      float* __restrict__ out) {
    __shared__ float prow[D];
    int g = blockIdx.x;
    int t = threadIdx.x;
    if (t < D) prow[t] = pooled[(size_t)g * D + t] / fmaxf(counts[g], 1.0f);
    __syncthreads();
    if (t < N_TARGETS) {
        float acc = bout[t];
#pragma unroll
        for (int k = 0; k < D; ++k)
            acc = fmaf(prow[k], Wout[k * N_TARGETS + t], acc);
        out[g * N_TARGETS + t] = acc;
    }
}

// ---------------- driver ----------------

extern "C" void kernel_launch(void* const* d_in, const int* in_sizes, int n_in,
                              void* d_out, int out_size, void* d_ws, size_t ws_size,
                              hipStream_t stream) {
    const float* x    = (const float*)d_in[0];
    const float* W1   = (const float*)d_in[1];
    const float* b1   = (const float*)d_in[2];
    const float* W2   = (const float*)d_in[3];
    const float* b2   = (const float*)d_in[4];
    const float* W3   = (const float*)d_in[5];
    const float* b3   = (const float*)d_in[6];
    const float* Wout = (const float*)d_in[7];
    const float* bout = (const float*)d_in[8];
    const int*   eidx = (const int*)d_in[9];
    const int*   seg  = (const int*)d_in[10];
    const int* src = eidx;
    const int* dst = eidx + N_EDGES;
    float* out = (float*)d_out;

    // workspace layout (~47 MB)
    _Float16* H16    = (_Float16*)d_ws;                      // 6,400,000 halfs (12.8MB)
    float*    bufB   = (float*)(H16 + (size_t)N_NODES * D);  // 6,400,000 floats (AGG)
    int*      esrc   = (int*)(bufB + (size_t)N_NODES * D);   // 1,600,000
    float*    dinv   = (float*)(esrc + N_EDGES);             // 100,000
    int*      degc   = (int*)(dinv + N_NODES);               // 100,000
    int*      base   = degc + N_NODES;                       // 100,001 (+pad)
    int*      bsum   = base + N_NODES + 4;                   // 512
    float*    pooled = (float*)(bsum + 512);                 // 32,768
    float*    counts = pooled + N_GRAPHS * D;                // 512

    const int NB = (N_NODES + 255) / 256;  // 391

    // ---- CSR build ----
    k_zero_i<<<NB, 256, 0, stream>>>(degc, N_NODES);
    k_deg<<<N_EDGES / 256, 256, 0, stream>>>(dst, degc);
    k_dinv<<<NB, 256, 0, stream>>>(degc, dinv);
    k_scan1<<<NB, 256, 0, stream>>>(degc, base, bsum);
    k_scan2<<<1, 512, 0, stream>>>(bsum, NB);
    k_scan3<<<NB, 256, 0, stream>>>(base, bsum, degc);
    k_fill<<<N_EDGES / 256, 256, 0, stream>>>(src, dst, base, degc, esrc);

    // ---- 3 GCN layers ----
    const int MMB = (N_NODES + 63) / 64;  // 1563
    k_mm<<<MMB, 256, 0, stream>>>(x, W1, dinv, H16, 0);
    k_pull<<<N_NODES / 4, 256, 0, stream>>>(H16, esrc, base, dinv, b1, bufB);
    k_mm<<<MMB, 256, 0, stream>>>(bufB, W2, dinv, H16, 1);
    k_pull<<<N_NODES / 4, 256, 0, stream>>>(H16, esrc, base, dinv, b2, bufB);
    k_mm<<<MMB, 256, 0, stream>>>(bufB, W3, dinv, H16, 1);
    k_pull<<<N_NODES / 4, 256, 0, stream>>>(H16, esrc, base, dinv, b3, bufB);

    // ---- mean pool (sorted-segment) + head ----
    k_zero_f<<<(N_GRAPHS * D + N_GRAPHS + 255) / 256, 256, 0, stream>>>(pooled, N_GRAPHS * D + N_GRAPHS);
    k_counts<<<NB, 256, 0, stream>>>(seg, counts);
    k_pool_seg<<<NB, 256, 0, stream>>>(bufB, seg, pooled);

    k_out<<<N_GRAPHS, 128, 0, stream>>>(pooled, counts, Wout, bout, out);
}